// Round 1
// baseline (46.720 us; speedup 1.0000x reference)
//
#include <hip/hip_runtime.h>

// ClusteringLayer: q[n,k] = normalize_k( 1 / (1 + ||x_n - c_k||^2) )
// x: [65536,256] fp32, clusters: [256,256] fp32, out: [65536,256] fp32.
// Memory-bound: 128 MB min traffic -> ~20 us floor. GEMM via f16 MFMA.

typedef _Float16 f16x8 __attribute__((ext_vector_type(8)));
typedef float    f32x4 __attribute__((ext_vector_type(4)));

#define DIM    256
#define NCLUST 256
#define BM     64

// ---------------------------------------------------------------------------
// Pre-kernel: blocks 0..127  -> clusters fp32 -> f16 MFMA-fragment order in ws
//             blocks 128..383 -> c2[j] = sum_d clusters[j][d]^2
// B-fragment order: index ((s*16 + t)*64 + lane), 8 halves each, holding
// B[n = t*16 + (lane&15)][k = s*32 + (lane>>4)*8 + v]  (v = 0..7 linear).
// ---------------------------------------------------------------------------
__global__ __launch_bounds__(64) void pre_kernel(const float* __restrict__ clusters,
                                                 _Float16* __restrict__ bfrag,
                                                 float* __restrict__ c2) {
    int b = blockIdx.x;
    int l = threadIdx.x;  // 64 threads
    if (b < 128) {
        int s  = b >> 4;
        int t  = b & 15;
        int n  = t * 16 + (l & 15);
        int k0 = s * 32 + (l >> 4) * 8;
        const f32x4* p = reinterpret_cast<const f32x4*>(clusters + n * DIM + k0);
        f32x4 a = p[0];
        f32x4 c = p[1];
        f16x8 h;
        h[0] = (_Float16)a[0]; h[1] = (_Float16)a[1];
        h[2] = (_Float16)a[2]; h[3] = (_Float16)a[3];
        h[4] = (_Float16)c[0]; h[5] = (_Float16)c[1];
        h[6] = (_Float16)c[2]; h[7] = (_Float16)c[3];
        reinterpret_cast<f16x8*>(bfrag)[b * 64 + l] = h;
    } else {
        int j = b - 128;
        const f32x4* p = reinterpret_cast<const f32x4*>(clusters + j * DIM);
        f32x4 v = p[l];
        float s = v[0] * v[0] + v[1] * v[1] + v[2] * v[2] + v[3] * v[3];
#pragma unroll
        for (int m = 32; m >= 1; m >>= 1) s += __shfl_xor(s, m, 64);
        if (l == 0) c2[j] = s;
    }
}

// ---------------------------------------------------------------------------
// Main kernel: 1024 blocks x 256 threads (4 waves). Block handles 64 rows.
// Wave w computes rows [w*16, w*16+16) x all 256 cluster columns
// as 16 tiles of mfma_f32_16x16x32_f16 over K=256 (8 steps).
// ---------------------------------------------------------------------------
__global__ __launch_bounds__(256, 2) void cluster_kernel(const float* __restrict__ x,
                                                         const f16x8* __restrict__ bfrag,
                                                         const float* __restrict__ c2,
                                                         float* __restrict__ out) {
    __shared__ _Float16 Xs[BM * DIM];   // 32 KB, XOR-swizzled rows
    __shared__ float    x2s[BM];
    __shared__ float    c2s[NCLUST];

    const int tid  = threadIdx.x;
    const int lane = tid & 63;
    const int wave = tid >> 6;
    const int row0 = blockIdx.x * BM;
    const float* xblk = x + (size_t)row0 * DIM;

    // ---- Stage X fp32 -> f16 LDS (coalesced 32B/thread/iter), fp32 row x2 ----
#pragma unroll
    for (int i = 0; i < 8; ++i) {
        int chunk = tid + i * 256;        // 32B-chunk id; 32 chunks per row
        int r  = chunk >> 5;              // 0..63
        int c8 = chunk & 31;              // 8-float group within row
        const f32x4* p = reinterpret_cast<const f32x4*>(xblk + r * DIM + c8 * 8);
        f32x4 a = p[0];
        f32x4 b = p[1];
        float s = a[0]*a[0] + a[1]*a[1] + a[2]*a[2] + a[3]*a[3]
                + b[0]*b[0] + b[1]*b[1] + b[2]*b[2] + b[3]*b[3];
        // 32 consecutive lanes share one row r: reduce within 32-lane halves
        s += __shfl_xor(s, 16, 64);
        s += __shfl_xor(s, 8, 64);
        s += __shfl_xor(s, 4, 64);
        s += __shfl_xor(s, 2, 64);
        s += __shfl_xor(s, 1, 64);
        if ((lane & 31) == 0) x2s[r] = s;

        f16x8 h;
        h[0] = (_Float16)a[0]; h[1] = (_Float16)a[1];
        h[2] = (_Float16)a[2]; h[3] = (_Float16)a[3];
        h[4] = (_Float16)b[0]; h[5] = (_Float16)b[1];
        h[6] = (_Float16)b[2]; h[7] = (_Float16)b[3];
        int byte = (r << 9) + (c8 << 4);
        byte ^= (r & 7) << 4;             // bank-conflict swizzle
        *reinterpret_cast<f16x8*>(reinterpret_cast<char*>(Xs) + byte) = h;
    }
    c2s[tid] = c2[tid];
    __syncthreads();

    // ---- K loop: A from LDS, B fragments straight from global (L1/L2-hit) ----
    f32x4 acc[16];
#pragma unroll
    for (int t = 0; t < 16; ++t) {
        acc[t][0] = 0.0f; acc[t][1] = 0.0f; acc[t][2] = 0.0f; acc[t][3] = 0.0f;
    }

    const int cl   = lane & 15;
    const int g    = lane >> 4;
    const int arow = wave * 16 + cl;           // A free index = lane&15
    const int alin = (arow << 9) + (g << 4);   // linear byte offset (pre-swizzle)
    const int aswz = (arow & 7) << 4;

#pragma unroll 1
    for (int s = 0; s < 8; ++s) {
        f16x8 af = *reinterpret_cast<const f16x8*>(
            reinterpret_cast<const char*>(Xs) + ((alin + (s << 6)) ^ aswz));
        const f16x8* bp = bfrag + ((s << 4) * 64 + lane);
#pragma unroll
        for (int t = 0; t < 16; ++t) {
            f16x8 bf = bp[t * 64];
            acc[t] = __builtin_amdgcn_mfma_f32_16x16x32_f16(af, bf, acc[t], 0, 0, 0);
        }
    }

    // ---- Epilogue: q = 1/(1+dist2), row-normalize, store fp32 ----
    // C/D layout (measured): col = lane&15, row = (lane>>4)*4 + reg.
    const int rloc = wave * 16 + g * 4;
    float x2j[4];
#pragma unroll
    for (int j = 0; j < 4; ++j) x2j[j] = x2s[rloc + j];

    float rsj[4] = {0.0f, 0.0f, 0.0f, 0.0f};
#pragma unroll
    for (int t = 0; t < 16; ++t) {
        float cc = c2s[t * 16 + cl];
#pragma unroll
        for (int j = 0; j < 4; ++j) {
            float d2 = x2j[j] + cc - 2.0f * acc[t][j];
            float q  = __builtin_amdgcn_rcpf(1.0f + d2);
            acc[t][j] = q;
            rsj[j] += q;
        }
    }
    // row lives in one 16-lane group: xor-reduce with masks 1,2,4,8
#pragma unroll
    for (int j = 0; j < 4; ++j) {
        float v = rsj[j];
        v += __shfl_xor(v, 1, 64);
        v += __shfl_xor(v, 2, 64);
        v += __shfl_xor(v, 4, 64);
        v += __shfl_xor(v, 8, 64);
        rsj[j] = __builtin_amdgcn_rcpf(v);
    }
#pragma unroll
    for (int j = 0; j < 4; ++j) {
        float* op = out + (size_t)(row0 + rloc + j) * NCLUST + cl;
        float rn = rsj[j];
#pragma unroll
        for (int t = 0; t < 16; ++t) op[t * 16] = acc[t][j] * rn;
    }
}

extern "C" void kernel_launch(void* const* d_in, const int* in_sizes, int n_in,
                              void* d_out, int out_size, void* d_ws, size_t ws_size,
                              hipStream_t stream) {
    const float* x        = (const float*)d_in[0];
    const float* clusters = (const float*)d_in[1];
    float* out = (float*)d_out;

    _Float16* bfrag = (_Float16*)d_ws;                       // 128*64*16 = 128 KB
    float*    c2    = (float*)((char*)d_ws + 128 * 64 * 16); // 1 KB

    pre_kernel<<<384, 64, 0, stream>>>(clusters, bfrag, c2);

    int nrows = in_sizes[0] / DIM;          // 65536
    int grid  = nrows / BM;                 // 1024
    cluster_kernel<<<grid, 256, 0, stream>>>(x, (const f16x8*)bfrag, c2, out);
}